// Round 7
// baseline (125.312 us; speedup 1.0000x reference)
//
#include <hip/hip_runtime.h>
#include <stdint.h>

typedef __attribute__((ext_vector_type(8))) short short8;
typedef __attribute__((ext_vector_type(4))) float f32x4;

#define BB 8
#define CC 256
#define PP 1024
#define NH 4
#define DH 64

__device__ __forceinline__ unsigned short f2bf(float f) {
  union { float f; unsigned u; } v; v.f = f;
  unsigned r = v.u + 0x7FFFu + ((v.u >> 16) & 1u);
  return (unsigned short)(r >> 16);
}

__device__ __forceinline__ float bf2f(unsigned short u) {
  union { unsigned u; float f; } v; v.u = ((unsigned)u) << 16;
  return v.f;
}

__device__ __forceinline__ f32x4 mfma16(short8 a, short8 b, f32x4 c) {
  return __builtin_amdgcn_mfma_f32_16x16x32_bf16(a, b, c, 0, 0, 0);
}

// -------- Kernel 1: GroupNorm partial sums (512 blk) + weight cvt (256 blk) -
__global__ __launch_bounds__(256) void prep(
    const float* __restrict__ x, float2* __restrict__ part,
    const float* __restrict__ qkvw, const float* __restrict__ projw,
    unsigned short* __restrict__ wall) {
  int blk = blockIdx.x;
  int tid = threadIdx.x;
  if (blk < 512) {
    int sl = blk & 7, g = (blk >> 3) & 7, b = blk >> 6;
    const float4* xb =
        (const float4*)(x + (size_t)(b * CC + g * 32) * PP) + sl * 1024;
    float s = 0.f, q = 0.f;
    for (int i = tid; i < 1024; i += 256) {
      float4 v = xb[i];
      s += v.x + v.y + v.z + v.w;
      q += v.x * v.x + v.y * v.y + v.z * v.z + v.w * v.w;
    }
    for (int off = 32; off > 0; off >>= 1) {
      s += __shfl_down(s, off);
      q += __shfl_down(q, off);
    }
    __shared__ float rs[4], rq[4];
    int w = tid >> 6;
    if ((tid & 63) == 0) { rs[w] = s; rq[w] = q; }
    __syncthreads();
    if (tid == 0)
      part[blk] = make_float2(rs[0] + rs[1] + rs[2] + rs[3],
                              rq[0] + rq[1] + rq[2] + rq[3]);
  } else {
    int i4 = (blk - 512) * 256 + tid;  // 65536 float4s total
    float4 v = (i4 < 49152) ? ((const float4*)qkvw)[i4]
                            : ((const float4*)projw)[i4 - 49152];
    ushort4 o;
    o.x = f2bf(v.x); o.y = f2bf(v.y); o.z = f2bf(v.z); o.w = f2bf(v.w);
    ((ushort4*)wall)[i4] = o;
  }
}

// ------------- Kernel 2: finish stats + normalize + transpose --------------
// -> xnT[b][p][c] bf16
__global__ __launch_bounds__(256) void norm_t(
    const float* __restrict__ x, const float2* __restrict__ part,
    const float* __restrict__ gamma, const float* __restrict__ beta,
    unsigned short* __restrict__ xnT) {
  int p0 = blockIdx.x * 64, c0 = blockIdx.y * 64, b = blockIdx.z;
  int tid = threadIdx.x;
  __shared__ float ms[2], rstd[2];
  __shared__ unsigned short T[64][72];
  if (tid < 2) {
    int g = blockIdx.y * 2 + tid;
    float S = 0.f, Q = 0.f;
    for (int i = 0; i < 8; ++i) {
      float2 pp = part[b * 64 + g * 8 + i];
      S += pp.x; Q += pp.y;
    }
    float mean = S * (1.f / 32768.f);
    float var = Q * (1.f / 32768.f) - mean * mean;
    ms[tid] = mean;
    rstd[tid] = rsqrtf(var + 1e-5f);
  }
  __syncthreads();
  for (int it = 0; it < 4; ++it) {
    int l = tid + 256 * it;
    int cc = l >> 4, p4 = l & 15;
    int c = c0 + cc, gi = cc >> 5;
    float sc = rstd[gi] * gamma[c];
    float sh = beta[c] - ms[gi] * sc;
    float4 v = *(const float4*)(x + (size_t)(b * CC + c) * PP + p0 + p4 * 4);
    T[p4 * 4 + 0][cc] = f2bf(v.x * sc + sh);
    T[p4 * 4 + 1][cc] = f2bf(v.y * sc + sh);
    T[p4 * 4 + 2][cc] = f2bf(v.z * sc + sh);
    T[p4 * 4 + 3][cc] = f2bf(v.w * sc + sh);
  }
  __syncthreads();
  for (int it = 0; it < 2; ++it) {
    int l = tid + 256 * it;
    int p = l >> 3, seg = l & 7;
    *(short8*)(xnT + ((size_t)b * PP + p0 + p) * CC + c0 + seg * 8) =
        *(const short8*)&T[p][seg * 8];
  }
}

// ------------- Kernel 3: QKV GEMM (computed [p][o]) ------------------------
// q,k: [b][h][p][64]; v stored TRANSPOSED: vT[b][h][ch][p]
__global__ __launch_bounds__(256) void qkv_gemm(
    const unsigned short* __restrict__ xnT, const unsigned short* __restrict__ wbf,
    const float* __restrict__ qkvb, unsigned short* __restrict__ qb,
    unsigned short* __restrict__ kb, unsigned short* __restrict__ vT) {
  int p0 = blockIdx.x * 128, o0 = blockIdx.y * 128, b = blockIdx.z;
  int tid = threadIdx.x;
  int w = tid >> 6, lane = tid & 63, lq = lane >> 4, ln = lane & 15;
  int wy = w >> 1, wx = w & 1;
  __shared__ unsigned short A_l[128][40];
  __shared__ unsigned short B_l[128][40];
  f32x4 acc[4][4];
  for (int i = 0; i < 4; ++i)
    for (int j = 0; j < 4; ++j) acc[i][j] = (f32x4){0.f, 0.f, 0.f, 0.f};
  for (int kc = 0; kc < 256; kc += 32) {
    for (int it = 0; it < 2; ++it) {
      int l = tid + 256 * it;
      int row = l >> 2, seg = l & 3;
      *(short8*)&A_l[row][seg * 8] =
          *(const short8*)(xnT + ((size_t)b * PP + p0 + row) * CC + kc + seg * 8);
      *(short8*)&B_l[row][seg * 8] =
          *(const short8*)(wbf + (size_t)(o0 + row) * CC + kc + seg * 8);
    }
    __syncthreads();
    short8 af[4], bf[4];
    for (int i = 0; i < 4; ++i)
      af[i] = *(const short8*)&A_l[wy * 64 + i * 16 + ln][lq * 8];
    for (int j = 0; j < 4; ++j)
      bf[j] = *(const short8*)&B_l[wx * 64 + j * 16 + ln][lq * 8];
    for (int i = 0; i < 4; ++i)
      for (int j = 0; j < 4; ++j) acc[i][j] = mfma16(af[i], bf[j], acc[i][j]);
    __syncthreads();
  }
  for (int i = 0; i < 4; ++i) {
    for (int j = 0; j < 4; ++j) {
      int o = o0 + wx * 64 + j * 16 + ln;
      int s = o >> 8, h = (o >> 6) & 3, ch = o & 63;
      float bias = qkvb[o];
      float mul = (s == 0) ? 0.125f : 1.0f;  // fold dh^-0.5 into q
      size_t bh = (size_t)b * NH + h;
      for (int r = 0; r < 4; ++r) {
        int p = p0 + wy * 64 + i * 16 + lq * 4 + r;
        unsigned short val = f2bf((acc[i][j][r] + bias) * mul);
        if (s == 2) {
          vT[(bh * DH + ch) * PP + p] = val;
        } else {
          unsigned short* dst = (s == 0) ? qb : kb;
          dst[(bh * PP + p) * DH + ch] = val;
        }
      }
    }
  }
}

// ------------- Kernel 4: flash attention, e-split waves --------------------
// Wave w owns e-window [w*32, w*32+32) of each 128-e tile and computes a
// PARTIAL O over its window for ALL 64 d x 64 ch (Q held as 8 register
// frags). QK: A=K rows e (4 b128), B=Q regs. PV: A=V rows ch (4 b128),
// B=P rows d (4 b128, own-wave window). Partials (bf16) + row-sums reduced
// across waves through LDS (aliased over dead K/V/P), output stored
// directly to global. No-max softmax safe: s=0.125*q.k ~ N(0,1); clamp 60.
__global__ __launch_bounds__(256) void attn(
    const unsigned short* __restrict__ qb, const unsigned short* __restrict__ kb,
    const unsigned short* __restrict__ vT, unsigned short* __restrict__ attnT) {
  int d0 = blockIdx.x * 64, h = blockIdx.y, b = blockIdx.z;
  int tid = threadIdx.x;
  int w = tid >> 6, lane = tid & 63, lq = lane >> 4, ln = lane & 15;
  size_t bh = (size_t)b * NH + h;
  const unsigned short* qbase = qb + bh * PP * DH;
  const unsigned short* kbase = kb + bh * PP * DH;
  const unsigned short* vbase = vT + bh * DH * PP;

  __shared__ __align__(16) char SM[53248];
  unsigned short (*K_l)[72] = (unsigned short (*)[72])(SM);            // 18432
  unsigned short (*V_l)[136] = (unsigned short (*)[136])(SM + 18432);  // 17408
  unsigned short (*P_l)[136] = (unsigned short (*)[136])(SM + 35840);  // 17408
  unsigned short* Obf = (unsigned short*)(SM);       // alias: 4*64*72*2 = 36864
  float* lsums = (float*)(SM + 36864);               // alias: 256*4 = 1024

  int ke = tid >> 1, kseg = tid & 1;   // K: 128 rows x 2 half-rows x 32 shorts
  int vch = tid >> 2, vseg = tid & 3;  // V: 64 rows x 4 quarter-rows x 32 shorts

  // Q frags for ALL 64 d: qf[ds][kc] = Q[d0+ds*16+ln][kc*32+lq*8 ..+7]
  short8 qf[4][2];
#pragma unroll
  for (int ds = 0; ds < 4; ++ds)
#pragma unroll
    for (int kc = 0; kc < 2; ++kc)
      qf[ds][kc] = *(const short8*)(qbase + (size_t)(d0 + ds * 16 + ln) * DH +
                                    kc * 32 + lq * 8);

  float lsum[4] = {0.f, 0.f, 0.f, 0.f};  // partial row-sums, col d = ds*16+ln
  f32x4 o_acc[4][4];                     // [cs][ds]: partial O over e-window
#pragma unroll
  for (int i = 0; i < 4; ++i)
#pragma unroll
    for (int j = 0; j < 4; ++j) o_acc[i][j] = (f32x4){0.f, 0.f, 0.f, 0.f};

  short8 kr[4], vr[4];
#pragma unroll
  for (int i = 0; i < 4; ++i)
    kr[i] = *(const short8*)(kbase + (size_t)ke * DH + kseg * 32 + i * 8);
#pragma unroll
  for (int i = 0; i < 4; ++i)
    vr[i] = *(const short8*)(vbase + (size_t)vch * PP + vseg * 32 + i * 8);

  for (int e0 = 0; e0 < PP; e0 += 128) {
#pragma unroll
    for (int i = 0; i < 4; ++i)
      *(short8*)&K_l[ke][kseg * 32 + i * 8] = kr[i];
#pragma unroll
    for (int i = 0; i < 4; ++i)
      *(short8*)&V_l[vch][vseg * 32 + i * 8] = vr[i];
    if (e0 + 128 < PP) {
      int en = e0 + 128;
#pragma unroll
      for (int i = 0; i < 4; ++i)
        kr[i] = *(const short8*)(kbase + (size_t)(en + ke) * DH + kseg * 32 + i * 8);
#pragma unroll
      for (int i = 0; i < 4; ++i)
        vr[i] = *(const short8*)(vbase + (size_t)vch * PP + en + vseg * 32 + i * 8);
    }
    __syncthreads();
    // QK: S^T[e in window][all 64 d]; 2 e-subtiles x 4 d-subtiles
#pragma unroll
    for (int es = 0; es < 2; ++es) {
      short8 ka0 = *(const short8*)&K_l[w * 32 + es * 16 + ln][lq * 8];
      short8 ka1 = *(const short8*)&K_l[w * 32 + es * 16 + ln][32 + lq * 8];
      f32x4 sc[4];
#pragma unroll
      for (int ds = 0; ds < 4; ++ds) {
        f32x4 a = (f32x4){0.f, 0.f, 0.f, 0.f};
        a = mfma16(ka0, qf[ds][0], a);
        a = mfma16(ka1, qf[ds][1], a);
        sc[ds] = a;  // col d = ds*16+ln, row e = w*32+es*16+lq*4+r
      }
#pragma unroll
      for (int ds = 0; ds < 4; ++ds) {
        float p0 = __expf(fminf(sc[ds][0], 60.f));
        float p1 = __expf(fminf(sc[ds][1], 60.f));
        float p2 = __expf(fminf(sc[ds][2], 60.f));
        float p3 = __expf(fminf(sc[ds][3], 60.f));
        lsum[ds] += (p0 + p1) + (p2 + p3);
        union { unsigned short u[4]; unsigned long long ll; } pk;
        pk.u[0] = f2bf(p0); pk.u[1] = f2bf(p1);
        pk.u[2] = f2bf(p2); pk.u[3] = f2bf(p3);
        *(unsigned long long*)&P_l[ds * 16 + ln][w * 32 + es * 16 + lq * 4] =
            pk.ll;
      }
    }
    // PV: partial O[ch][d] += sum_{e in window} V[ch][e] * P[d][e]
    short8 pb[4];
#pragma unroll
    for (int ds = 0; ds < 4; ++ds)
      pb[ds] = *(const short8*)&P_l[ds * 16 + ln][w * 32 + lq * 8];
#pragma unroll
    for (int cs = 0; cs < 4; ++cs) {
      short8 va = *(const short8*)&V_l[cs * 16 + ln][w * 32 + lq * 8];
#pragma unroll
      for (int ds = 0; ds < 4; ++ds)
        o_acc[cs][ds] = mfma16(va, pb[ds], o_acc[cs][ds]);
    }
    __syncthreads();
  }
  // ---- cross-wave reduction: partial row-sums + bf16 partial O -> LDS ----
#pragma unroll
  for (int ds = 0; ds < 4; ++ds) {
    float s = lsum[ds];
    s += __shfl_xor(s, 16);
    s += __shfl_xor(s, 32);
    if (lq == 0) lsums[w * 64 + ds * 16 + ln] = s;
  }
#pragma unroll
  for (int cs = 0; cs < 4; ++cs) {
#pragma unroll
    for (int ds = 0; ds < 4; ++ds) {
      union { unsigned short u[4]; unsigned long long ll; } pk;
#pragma unroll
      for (int r = 0; r < 4; ++r) pk.u[r] = f2bf(o_acc[cs][ds][r]);
      // Obf[w][d = ds*16+ln][ch = cs*16+lq*4 .. +3]
      *(unsigned long long*)&Obf[((w * 64 + ds * 16 + ln) * 72) + cs * 16 +
                                 lq * 4] = pk.ll;
    }
  }
  __syncthreads();
  // ---- final: sum 4 partials, normalize, store direct to global ----------
  {
    int d = tid >> 2, cr = tid & 3;
    float inv = 1.f / (lsums[d] + lsums[64 + d] + lsums[128 + d] + lsums[192 + d]);
    float o[16];
#pragma unroll
    for (int j = 0; j < 16; ++j) o[j] = 0.f;
#pragma unroll
    for (int ww = 0; ww < 4; ++ww) {
#pragma unroll
      for (int jj = 0; jj < 4; ++jj) {
        unsigned long long v = *(const unsigned long long*)&Obf[
            ((ww * 64 + d) * 72) + cr * 16 + jj * 4];
#pragma unroll
        for (int r = 0; r < 4; ++r)
          o[jj * 4 + r] += bf2f((unsigned short)(v >> (16 * r)));
      }
    }
    union { unsigned short u[16]; short8 s[2]; } pk;
#pragma unroll
    for (int j = 0; j < 16; ++j) pk.u[j] = f2bf(o[j] * inv);
    unsigned short* dst =
        attnT + ((size_t)b * PP + d0 + d) * CC + h * DH + cr * 16;
    *(short8*)dst = pk.s[0];
    *(short8*)(dst + 8) = pk.s[1];
  }
}

// ------------- Kernel 5: proj GEMM + bias + residual (fp32 out) ------------
__global__ __launch_bounds__(256) void proj_gemm(
    const unsigned short* __restrict__ attnT, const unsigned short* __restrict__ pwbf,
    const float* __restrict__ projb, const float* __restrict__ x,
    float* __restrict__ out) {
  int p0 = blockIdx.x * 128, o0 = blockIdx.y * 64, b = blockIdx.z;
  int tid = threadIdx.x;
  int w = tid >> 6, lane = tid & 63, lq = lane >> 4, ln = lane & 15;
  __shared__ unsigned short A_l[64][40];
  __shared__ unsigned short B_l[128][40];
  f32x4 acc[4][2];
  for (int i = 0; i < 4; ++i)
    for (int j = 0; j < 2; ++j) acc[i][j] = (f32x4){0.f, 0.f, 0.f, 0.f};
  for (int kc = 0; kc < 256; kc += 32) {
    {
      int row = tid >> 2, seg = tid & 3;
      *(short8*)&A_l[row][seg * 8] =
          *(const short8*)(pwbf + (size_t)(o0 + row) * CC + kc + seg * 8);
    }
    for (int it = 0; it < 2; ++it) {
      int l = tid + 256 * it;
      int row = l >> 2, seg = l & 3;
      *(short8*)&B_l[row][seg * 8] =
          *(const short8*)(attnT + ((size_t)b * PP + p0 + row) * CC + kc + seg * 8);
    }
    __syncthreads();
    short8 af[4], bfr[2];
    for (int i = 0; i < 4; ++i)
      af[i] = *(const short8*)&A_l[i * 16 + ln][lq * 8];
    for (int j = 0; j < 2; ++j)
      bfr[j] = *(const short8*)&B_l[w * 32 + j * 16 + ln][lq * 8];
    for (int i = 0; i < 4; ++i)
      for (int j = 0; j < 2; ++j) acc[i][j] = mfma16(af[i], bfr[j], acc[i][j]);
    __syncthreads();
  }
  for (int i = 0; i < 4; ++i) {
    for (int j = 0; j < 2; ++j) {
      int p = p0 + w * 32 + j * 16 + ln;
      for (int r = 0; r < 4; ++r) {
        int o = o0 + i * 16 + lq * 4 + r;
        size_t idx = ((size_t)b * CC + o) * PP + p;
        out[idx] = x[idx] + projb[o] + acc[i][j][r];
      }
    }
  }
}

// ---------------------------------------------------------------------------
extern "C" void kernel_launch(void* const* d_in, const int* in_sizes, int n_in,
                              void* d_out, int out_size, void* d_ws, size_t ws_size,
                              hipStream_t stream) {
  const float* x = (const float*)d_in[0];
  const float* gamma = (const float*)d_in[1];
  const float* beta = (const float*)d_in[2];
  const float* qkvw = (const float*)d_in[3];
  const float* qkvb = (const float*)d_in[4];
  const float* projw = (const float*)d_in[5];
  const float* projb = (const float*)d_in[6];
  float* out = (float*)d_out;
  char* ws = (char*)d_ws;

  float2* part = (float2*)(ws + 0);                        //  4 KB
  unsigned short* xnT = (unsigned short*)(ws + 16384);     //  4 MB
  unsigned short* wall = (unsigned short*)(ws + 4210688);  // 512 KB
  unsigned short* pwbf = wall + 768 * 256;
  unsigned short* qb = (unsigned short*)(ws + 4734976);      // 4 MB
  unsigned short* kb = (unsigned short*)(ws + 8929280);      // 4 MB
  unsigned short* vT = (unsigned short*)(ws + 13123584);     // 4 MB
  unsigned short* attnT = (unsigned short*)(ws + 17317888);  // 4 MB

  prep<<<768, 256, 0, stream>>>(x, part, qkvw, projw, wall);
  norm_t<<<dim3(16, 4, 8), 256, 0, stream>>>(x, part, gamma, beta, xnT);
  qkv_gemm<<<dim3(8, 6, 8), 256, 0, stream>>>(xnT, wall, qkvb, qb, kb, vT);
  attn<<<dim3(16, 4, 8), 256, 0, stream>>>(qb, kb, vT, attnT);
  proj_gemm<<<dim3(8, 4, 8), 256, 0, stream>>>(attnT, pwbf, projb, x, out);
}